// Round 20
// baseline (622.532 us; speedup 1.0000x reference)
//
#include <hip/hip_runtime.h>
#include <hip/hip_bf16.h>

// ---------------------------------------------------------------------------
// GIN forward, round 20 (base = r19, 588us best):
//   - GEMM1 retiled 256x128 -> 256x160: staged bytes 240 -> 208 MB while
//     KEEPING 2-residency (LDS 78KB x2 = 156 <= 160; launch_bounds(256,2)),
//     which r18 showed protects against round-quantization. Schedule is the
//     r12-proven form; staging split is wave-uniform uneven (w0-1: 7 loads,
//     w2-3: 6) with the per-wave vmcnt split validated in r19's gemm_w160.
//   - GEMM2 (w160) and everything else unchanged from r19.
// ---------------------------------------------------------------------------

#define N_NODES 50000
#define M_P     50176      // 98 * 512 = 196 * 256
#define N_EDGES 200000
#define IN_DIM  64
#define EMB     300
#define HID     600
#define EMB_P   320        // hbuf row stride / GEMM2 N (2 * 160)
#define EMB_K   320        // zin row stride / GEMM1 K (10 * 32)
#define HID_P   640        // GEMM1 N (4 * 160)
#define N_GRAPHS 1024
#define N_CLASS 10
#define BN_EPS  1e-5f

typedef _Float16 half8 __attribute__((ext_vector_type(8)));
typedef float    f32x4 __attribute__((ext_vector_type(4)));

__device__ __forceinline__ void gload16(const void* g, void* l) {
    __builtin_amdgcn_global_load_lds(
        (const __attribute__((address_space(1))) void*)g,
        (__attribute__((address_space(3))) void*)l, 16, 0, 0);
}

// ---------------- CSR build ----------------

__global__ void count_deg_kernel(const int* __restrict__ dst, int* __restrict__ deg, int E) {
    int e = blockIdx.x * blockDim.x + threadIdx.x;
    if (e < E) atomicAdd(&deg[dst[e]], 1);
}

__global__ void block_reduce_kernel(const int* __restrict__ in, int* __restrict__ partials, int n) {
    __shared__ int sm[4];
    const int b = blockIdx.x, t = threadIdx.x;
    const int base = b * 1024;
    int v = 0;
    #pragma unroll
    for (int i = 0; i < 4; ++i) {
        int ix = base + t + i * 256;
        if (ix < n) v += in[ix];
    }
    #pragma unroll
    for (int off = 32; off > 0; off >>= 1) v += __shfl_xor(v, off);
    if ((t & 63) == 0) sm[t >> 6] = v;
    __syncthreads();
    if (t == 0) partials[b] = sm[0] + sm[1] + sm[2] + sm[3];
}

__global__ void scan_partials_kernel(int* __restrict__ partials, int nb) {
    const int t = threadIdx.x;
    int v = (t < nb) ? partials[t] : 0;
    const int orig = v;
    #pragma unroll
    for (int off = 1; off < 64; off <<= 1) {
        int u = __shfl_up(v, off);
        if (t >= off) v += u;
    }
    if (t < nb) partials[t] = v - orig;
}

__global__ void block_scan_kernel(const int* __restrict__ in, const int* __restrict__ partials,
                                  int* __restrict__ out, int* __restrict__ cursor,
                                  int n, int total) {
    __shared__ int sd[1024];
    const int b = blockIdx.x, t = threadIdx.x;
    const int idx = b * 1024 + t;
    const int v = (idx < n) ? in[idx] : 0;
    sd[t] = v;
    __syncthreads();
    #pragma unroll
    for (int off = 1; off < 1024; off <<= 1) {
        int u = (t >= off) ? sd[t - off] : 0;
        __syncthreads();
        sd[t] += u;
        __syncthreads();
    }
    if (idx < n) {
        int ex = partials[b] + sd[t] - v;
        out[idx] = ex;
        cursor[idx] = ex;
    }
    if (b == 0 && t == 0) out[n] = total;
}

__global__ void scatter_edges_kernel(const int* __restrict__ src, const int* __restrict__ dst,
                                     int* __restrict__ cursor, int* __restrict__ esrc, int E) {
    int e = blockIdx.x * blockDim.x + threadIdx.x;
    if (e < E) {
        int d = dst[e];
        int pos = atomicAdd(&cursor[d], 1);
        esrc[pos] = src[e];
    }
}

// ---------------- weight / epilogue-param conversion ----------------

__global__ void convert_w(const float* __restrict__ W, _Float16* __restrict__ Wt,
                          int K, int N, int K_P, int N_P) {
    int b = blockIdx.y;
    int i = blockIdx.x * 256 + threadIdx.x;
    if (i >= N_P * K_P) return;
    int n = i / K_P, k = i % K_P;
    _Float16 v = (_Float16)0.f;
    if (n < N && k < K) v = (_Float16)W[((size_t)b * K + k) * N + n];
    Wt[(size_t)b * N_P * K_P + i] = v;
}

__global__ void convert_st(const float* __restrict__ bias, const float* __restrict__ g,
                           const float* __restrict__ bb, const float* __restrict__ m,
                           const float* __restrict__ v, float* __restrict__ S,
                           float* __restrict__ T, int N, int N_P) {
    int b = blockIdx.y;
    int i = blockIdx.x * 256 + threadIdx.x;
    if (i >= N_P) return;
    float s = 0.f, t = 0.f;
    if (i < N) {
        s = g[b * N + i] * rsqrtf(v[b * N + i] + BN_EPS);
        t = (bias[b * N + i] - m[b * N + i]) * s + bb[b * N + i];
    }
    S[b * N_P + i] = s;
    T[b * N_P + i] = t;
}

// ---------------- aggregation ----------------

__global__ void aggregate_f16(const _Float16* __restrict__ h, const int* __restrict__ rowptr,
                              const int* __restrict__ esrc, _Float16* __restrict__ z) {
    const int NCH = EMB_K / 8;          // 40
    const int NACT = 38;                // ceil(300/8); h cols 300..319 are 0
    int t = blockIdx.x * blockDim.x + threadIdx.x;
    int node = t / NCH;
    int c = t - node * NCH;
    if (node >= N_NODES) return;
    _Float16* zp = z + (size_t)node * EMB_K + c * 8;
    if (c >= NACT) {
        half8 zero = {};
        *(half8*)zp = zero;
        return;
    }
    float a[8];
    half8 v = *(const half8*)(h + (size_t)node * EMB_P + c * 8);
    #pragma unroll
    for (int j = 0; j < 8; ++j) a[j] = (float)v[j];
    int s0 = rowptr[node], s1 = rowptr[node + 1];
    for (int e = s0; e < s1; ++e) {
        half8 u = *(const half8*)(h + (size_t)esrc[e] * EMB_P + c * 8);
        #pragma unroll
        for (int j = 0; j < 8; ++j) a[j] += (float)u[j];
    }
    half8 o;
    #pragma unroll
    for (int j = 0; j < 8; ++j) o[j] = (_Float16)a[j];
    *(half8*)zp = o;
}

__global__ void aggregate_f32in(const float* __restrict__ x, const int* __restrict__ rowptr,
                                const int* __restrict__ esrc, _Float16* __restrict__ z) {
    int t = blockIdx.x * blockDim.x + threadIdx.x;
    int node = t >> 4;
    int c = t & 15;
    if (node >= N_NODES) return;
    float4 a = *(const float4*)(x + (size_t)node * IN_DIM + c * 4);
    int s0 = rowptr[node], s1 = rowptr[node + 1];
    for (int e = s0; e < s1; ++e) {
        float4 u = *(const float4*)(x + (size_t)esrc[e] * IN_DIM + c * 4);
        a.x += u.x; a.y += u.y; a.z += u.z; a.w += u.w;
    }
    _Float16* zp = z + (size_t)node * IN_DIM + c * 4;
    zp[0] = (_Float16)a.x; zp[1] = (_Float16)a.y;
    zp[2] = (_Float16)a.z; zp[3] = (_Float16)a.w;
}

// ---------------- GEMM1: 256x160 tile, 4 waves, 2-resident ----------------
// Wave tile 128x80 (2M x 2N). LDS 78KB: A 3 x 8192 halves (16KB), B 3 x
// 5120 halves (10KB). Staging: per wave 4 A subtiles (wid+4j); B subtiles
// w0:{0,1,2} w1:{3,4,5} w2:{6,7} w3:{8,9} (each exactly once). Per-wave
// loads 7/7/6/6 -> wave-uniform vmcnt split (r19-proven). Schedule r12-form.

template<int KP>
__global__ __launch_bounds__(256, 2) void gemm_t160(
        const _Float16* __restrict__ A, const _Float16* __restrict__ Bt,
        const float* __restrict__ Sc, const float* __restrict__ Tc,
        _Float16* __restrict__ C, int N_P, int do_relu) {
    constexpr int NT = KP / 32;
    __shared__ _Float16 LDS[3 * 8192 + 3 * 5120];   // 78 KB
    _Float16* const ABUF = LDS;
    _Float16* const BBUF = LDS + 3 * 8192;
    const int tid  = threadIdx.x;
    const int wid  = tid >> 6;                      // 0..3
    const int lane = tid & 63;

    const int NY  = N_P / 160;
    const int nwg = gridDim.x;
    const int q = nwg >> 3, r = nwg & 7;
    const int xcd = blockIdx.x & 7, bidx = blockIdx.x >> 3;
    const int wgid = (xcd < r ? xcd * (q + 1) : r * (q + 1) + (xcd - r) * q) + bidx;
    const int mt = wgid / NY;
    const int ntile = wgid - mt * NY;
    const size_t bm0 = (size_t)mt * 256;
    const int    bn0 = ntile * 160;

    const int wr = (wid & 1) * 128;          // 0/128
    const int wc = (wid >> 1) * 80;          // 0/80

    const int fr = lane & 15;
    const int fk = (lane >> 4) * 8;
    const _Float16* gA = A  + (bm0 + fr) * (size_t)KP + fk;
    const _Float16* gB = Bt + ((size_t)bn0 + fr) * (size_t)KP + fk;

    f32x4 acc[8][5];
    #pragma unroll
    for (int m = 0; m < 8; ++m)
        #pragma unroll
        for (int n = 0; n < 5; ++n) acc[m][n] = (f32x4){0.f, 0.f, 0.f, 0.f};

    const int subA = wr >> 4;                // 0/8  (A: 16 subtiles)
    const int subB = wc >> 4;                // 0/5  (B: 10 subtiles)

    // B subtile ranges per wave: w0 [0,3), w1 [3,6), w2 [6,8), w3 [8,10)
    const int b0 = (wid < 2) ? wid * 3 : 6 + (wid - 2) * 2;
    const int nb = (wid < 2) ? 3 : 2;

    auto stage = [&](int tt) {               // 7 loads (w0,w1) / 6 (w2,w3)
        const int k0 = tt * 32;
        _Float16* la = ABUF + (tt % 3) * 8192;
        #pragma unroll
        for (int j = 0; j < 4; ++j) {        // A subtiles wid + 4j (0..15)
            const int s = wid + 4 * j;
            gload16(gA + (size_t)(s * 16) * KP + k0, la + s * 512);
        }
        _Float16* lb = BBUF + (tt % 3) * 5120;
        for (int j = 0; j < nb; ++j) {       // nb wave-uniform
            const int s = b0 + j;
            gload16(gB + (size_t)(s * 16) * KP + k0, lb + s * 512);
        }
    };

    stage(0);
    if (NT > 1) stage(1);

    #pragma unroll
    for (int t = 0; t < NT; ++t) {
        if (t + 1 < NT) {
            if (wid < 2) asm volatile("s_waitcnt vmcnt(7)" ::: "memory");
            else         asm volatile("s_waitcnt vmcnt(6)" ::: "memory");
        } else {
            asm volatile("s_waitcnt vmcnt(0)" ::: "memory");
        }
        __builtin_amdgcn_s_barrier();            // all waves' stage(t) landed,
                                                 // all reads of iter t-1 done
        __builtin_amdgcn_sched_barrier(0);       // no hoisting above barrier
        if (t + 2 < NT) stage(t + 2);            // buf (t+2)%3, last read t-1
        {
            const _Float16* la = ABUF + (t % 3) * 8192;
            const _Float16* lb = BBUF + (t % 3) * 5120;
            half8 af[8], bf[5];
            #pragma unroll
            for (int m = 0; m < 8; ++m)
                af[m] = *(const half8*)(la + (subA + m) * 512 + lane * 8);
            #pragma unroll
            for (int n = 0; n < 5; ++n)
                bf[n] = *(const half8*)(lb + (subB + n) * 512 + lane * 8);
            __builtin_amdgcn_s_setprio(1);
            #pragma unroll
            for (int m = 0; m < 8; ++m)
                #pragma unroll
                for (int n = 0; n < 5; ++n)
                    acc[m][n] = __builtin_amdgcn_mfma_f32_16x16x32_f16(
                        af[m], bf[n], acc[m][n], 0, 0, 0);
            __builtin_amdgcn_s_setprio(0);
        }
    }

    #pragma unroll
    for (int n = 0; n < 5; ++n) {
        const int col = bn0 + wc + n * 16 + fr;
        const float s = Sc[col], t = Tc[col];
        #pragma unroll
        for (int m = 0; m < 8; ++m) {
            f32x4 v = acc[m][n];
            const size_t rbase = bm0 + wr + m * 16 + (lane >> 4) * 4;
            #pragma unroll
            for (int rr = 0; rr < 4; ++rr) {
                float y = v[rr] * s + t;
                if (do_relu) y = fmaxf(y, 0.f);
                C[(rbase + rr) * (size_t)N_P + col] = (_Float16)y;
            }
        }
    }
}

// ---------------- GEMM2: 512x160 tile (r19 exact) ----------------

template<int KP>
__global__ __launch_bounds__(512, 1) void gemm_w160(
        const _Float16* __restrict__ A, const _Float16* __restrict__ Bt,
        const float* __restrict__ Sc, const float* __restrict__ Tc,
        _Float16* __restrict__ C, int N_P, int do_relu) {
    constexpr int NT = KP / 32;
    __shared__ _Float16 LDS[3 * 16384 + 3 * 5120];  // 126 KB
    _Float16* const ABUF = LDS;
    _Float16* const BBUF = LDS + 3 * 16384;
    const int tid  = threadIdx.x;
    const int wid  = tid >> 6;                      // 0..7
    const int lane = tid & 63;

    const int NY  = N_P / 160;
    const int nwg = gridDim.x;
    const int q = nwg >> 3, r = nwg & 7;
    const int xcd = blockIdx.x & 7, bidx = blockIdx.x >> 3;
    const int wgid = (xcd < r ? xcd * (q + 1) : r * (q + 1) + (xcd - r) * q) + bidx;
    const int mt = wgid / NY;
    const int ntile = wgid - mt * NY;
    const size_t bm0 = (size_t)mt * 512;
    const int    bn0 = ntile * 160;

    const int wr = (wid & 3) * 128;          // 0/128/256/384
    const int wc = (wid >> 2) * 80;          // 0/80

    const int fr = lane & 15;
    const int fk = (lane >> 4) * 8;
    const _Float16* gA = A  + (bm0 + fr) * (size_t)KP + fk;
    const _Float16* gB = Bt + ((size_t)bn0 + fr) * (size_t)KP + fk;

    f32x4 acc[8][5];
    #pragma unroll
    for (int m = 0; m < 8; ++m)
        #pragma unroll
        for (int n = 0; n < 5; ++n) acc[m][n] = (f32x4){0.f, 0.f, 0.f, 0.f};

    const int subA = wr >> 4;                // 0/8/16/24 (A: 32 subtiles)
    const int subB = wc >> 4;                // 0/5       (B: 10 subtiles)

    auto stage = [&](int tt) {               // w0-4: 6 loads; w5-7: 4 loads
        const int k0 = tt * 32;
        _Float16* la = ABUF + (tt % 3) * 16384;
        #pragma unroll
        for (int j = 0; j < 4; ++j) {        // A subtiles wid + 8j (0..31)
            const int s = wid + 8 * j;
            gload16(gA + (size_t)(s * 16) * KP + k0, la + s * 512);
        }
        if (wid < 5) {                       // B subtiles 2*wid, 2*wid+1 (0..9)
            _Float16* lb = BBUF + (tt % 3) * 5120;
            #pragma unroll
            for (int j = 0; j < 2; ++j) {
                const int s = 2 * wid + j;
                gload16(gB + (size_t)(s * 16) * KP + k0, lb + s * 512);
            }
        }
    };

    stage(0);
    if (NT > 1) stage(1);

    #pragma unroll
    for (int t = 0; t < NT; ++t) {
        if (t + 1 < NT) {
            if (wid < 5) asm volatile("s_waitcnt vmcnt(6)" ::: "memory");
            else         asm volatile("s_waitcnt vmcnt(4)" ::: "memory");
        } else {
            asm volatile("s_waitcnt vmcnt(0)" ::: "memory");
        }
        __builtin_amdgcn_s_barrier();
        __builtin_amdgcn_sched_barrier(0);
        if (t + 2 < NT) stage(t + 2);
        {
            const _Float16* la = ABUF + (t % 3) * 16384;
            const _Float16* lb = BBUF + (t % 3) * 5120;
            half8 af[8], bf[5];
            #pragma unroll
            for (int m = 0; m < 8; ++m)
                af[m] = *(const half8*)(la + (subA + m) * 512 + lane * 8);
            #pragma unroll
            for (int n = 0; n < 5; ++n)
                bf[n] = *(const half8*)(lb + (subB + n) * 512 + lane * 8);
            __builtin_amdgcn_s_setprio(1);
            #pragma unroll
            for (int m = 0; m < 8; ++m)
                #pragma unroll
                for (int n = 0; n < 5; ++n)
                    acc[m][n] = __builtin_amdgcn_mfma_f32_16x16x32_f16(
                        af[m], bf[n], acc[m][n], 0, 0, 0);
            __builtin_amdgcn_s_setprio(0);
        }
    }

    #pragma unroll
    for (int n = 0; n < 5; ++n) {
        const int col = bn0 + wc + n * 16 + fr;
        const float s = Sc[col], t = Tc[col];
        #pragma unroll
        for (int m = 0; m < 8; ++m) {
            f32x4 v = acc[m][n];
            const size_t rbase = bm0 + wr + m * 16 + (lane >> 4) * 4;
            #pragma unroll
            for (int rr = 0; rr < 4; ++rr) {
                float y = v[rr] * s + t;
                if (do_relu) y = fmaxf(y, 0.f);
                C[(rbase + rr) * (size_t)N_P + col] = (_Float16)y;
            }
        }
    }
}

// ---------------- mean pool + classifier ----------------

__global__ void pool_classify(const _Float16* __restrict__ h, const int* __restrict__ batch,
                              const float* __restrict__ clfW, const float* __restrict__ clfb,
                              float* __restrict__ out, int n) {
    int g = blockIdx.x;
    __shared__ int s_lo, s_hi;
    __shared__ float pooled[304];
    if (threadIdx.x == 0) {
        int lo = 0, hi = n;
        while (lo < hi) { int mid = (lo + hi) >> 1; if (batch[mid] < g) lo = mid + 1; else hi = mid; }
        s_lo = lo;
        int lo2 = lo, hi2 = n;
        while (lo2 < hi2) { int mid = (lo2 + hi2) >> 1; if (batch[mid] < g + 1) lo2 = mid + 1; else hi2 = mid; }
        s_hi = lo2;
    }
    __syncthreads();
    const int lo = s_lo, hi = s_hi;
    const float inv = 1.0f / fmaxf((float)(hi - lo), 1.0f);
    const int c = threadIdx.x;
    if (c < 38) {
        float a[8] = {0.f, 0.f, 0.f, 0.f, 0.f, 0.f, 0.f, 0.f};
        for (int r = lo; r < hi; ++r) {
            half8 v = *(const half8*)(h + (size_t)r * EMB_P + c * 8);
            #pragma unroll
            for (int j = 0; j < 8; ++j) a[j] += (float)v[j];
        }
        #pragma unroll
        for (int j = 0; j < 8; ++j) pooled[c * 8 + j] = a[j] * inv;
    }
    __syncthreads();
    const int lane = threadIdx.x & 63;
    for (int cc = 0; cc < N_CLASS; ++cc) {
        float p = 0.f;
        for (int d = lane; d < EMB; d += 64) p += pooled[d] * clfW[d * N_CLASS + cc];
        #pragma unroll
        for (int off = 32; off > 0; off >>= 1) p += __shfl_down(p, off);
        if (lane == 0) out[g * N_CLASS + cc] = p + clfb[cc];
    }
}

// ---------------- launch ----------------

extern "C" void kernel_launch(void* const* d_in, const int* in_sizes, int n_in,
                              void* d_out, int out_size, void* d_ws, size_t ws_size,
                              hipStream_t stream) {
    const float* x      = (const float*)d_in[0];
    const int*   ei     = (const int*)d_in[1];
    const int*   batch  = (const int*)d_in[2];
    const float* l1_W1  = (const float*)d_in[3];
    const float* l1_b1  = (const float*)d_in[4];
    const float* l1_bn_g = (const float*)d_in[5];
    const float* l1_bn_b = (const float*)d_in[6];
    const float* l1_bn_m = (const float*)d_in[7];
    const float* l1_bn_v = (const float*)d_in[8];
    const float* l1_W2  = (const float*)d_in[9];
    const float* l1_b2  = (const float*)d_in[10];
    const float* l1_bno_g = (const float*)d_in[11];
    const float* l1_bno_b = (const float*)d_in[12];
    const float* l1_bno_m = (const float*)d_in[13];
    const float* l1_bno_v = (const float*)d_in[14];
    const float* Ws1    = (const float*)d_in[15];
    const float* bs1    = (const float*)d_in[16];
    const float* bn_g   = (const float*)d_in[17];
    const float* bn_b   = (const float*)d_in[18];
    const float* bn_m   = (const float*)d_in[19];
    const float* bn_v   = (const float*)d_in[20];
    const float* Ws2    = (const float*)d_in[21];
    const float* bs2    = (const float*)d_in[22];
    const float* bno_g  = (const float*)d_in[23];
    const float* bno_b  = (const float*)d_in[24];
    const float* bno_m  = (const float*)d_in[25];
    const float* bno_v  = (const float*)d_in[26];
    const float* clfW   = (const float*)d_in[27];
    const float* clfb   = (const float*)d_in[28];
    float* out = (float*)d_out;

    const int N = N_NODES, E = N_EDGES;
    const int* src = ei;
    const int* dst = ei + E;

    char* ws = (char*)d_ws;
    size_t off = 0;
    auto alloc = [&](size_t bytes) -> void* {
        void* p = ws + off;
        off += (bytes + 255) & ~(size_t)255;
        return p;
    };
    _Float16* zmid  = (_Float16*)alloc((size_t)M_P * HID_P * 2);   // 64 MB
    _Float16* hbuf  = (_Float16*)alloc((size_t)M_P * EMB_P * 2);   // 32 MB
    _Float16* zin   = (_Float16*)alloc((size_t)M_P * EMB_K * 2);   // 32 MB
    _Float16* wt_l1a = (_Float16*)alloc((size_t)HID_P * IN_DIM * 2);
    _Float16* wt_l1b = (_Float16*)alloc((size_t)EMB_P * HID_P * 2);
    _Float16* wt1   = (_Float16*)alloc((size_t)4 * HID_P * EMB_K * 2);
    _Float16* wt2   = (_Float16*)alloc((size_t)4 * EMB_P * HID_P * 2);
    float* s_l1a = (float*)alloc(HID_P * 4); float* t_l1a = (float*)alloc(HID_P * 4);
    float* s_l1b = (float*)alloc(EMB_P * 4); float* t_l1b = (float*)alloc(EMB_P * 4);
    float* s1 = (float*)alloc(4 * HID_P * 4); float* t1 = (float*)alloc(4 * HID_P * 4);
    float* s2 = (float*)alloc(4 * EMB_P * 4); float* t2 = (float*)alloc(4 * EMB_P * 4);
    int* deg      = (int*)alloc((size_t)N * 4);
    int* rowptr   = (int*)alloc((size_t)(N + 1) * 4);
    int* cursor   = (int*)alloc((size_t)N * 4);
    int* esrc     = (int*)alloc((size_t)E * 4);
    int* partials = (int*)alloc(64 * 4);
    (void)ws_size; (void)n_in; (void)in_sizes; (void)out_size;

    const int NB_SCAN = (N + 1023) / 1024;   // 49

    // ---- CSR ----
    hipMemsetAsync(deg, 0, (size_t)N * 4, stream);
    count_deg_kernel<<<(E + 255) / 256, 256, 0, stream>>>(dst, deg, E);
    block_reduce_kernel<<<NB_SCAN, 256, 0, stream>>>(deg, partials, N);
    scan_partials_kernel<<<1, 64, 0, stream>>>(partials, NB_SCAN);
    block_scan_kernel<<<NB_SCAN, 1024, 0, stream>>>(deg, partials, rowptr, cursor, N, E);
    scatter_edges_kernel<<<(E + 255) / 256, 256, 0, stream>>>(src, dst, cursor, esrc, E);

    // ---- weight & epilogue-param conversion ----
    {
        dim3 g1((HID_P * IN_DIM + 255) / 256, 1);
        convert_w<<<g1, 256, 0, stream>>>(l1_W1, wt_l1a, IN_DIM, HID, IN_DIM, HID_P);
        dim3 g2((EMB_P * HID_P + 255) / 256, 1);
        convert_w<<<g2, 256, 0, stream>>>(l1_W2, wt_l1b, HID, EMB, HID_P, EMB_P);
        dim3 g3((HID_P * EMB_K + 255) / 256, 4);
        convert_w<<<g3, 256, 0, stream>>>(Ws1, wt1, EMB, HID, EMB_K, HID_P);
        dim3 g4((EMB_P * HID_P + 255) / 256, 4);
        convert_w<<<g4, 256, 0, stream>>>(Ws2, wt2, HID, EMB, HID_P, EMB_P);

        dim3 s1g((HID_P + 255) / 256, 1);
        convert_st<<<s1g, 256, 0, stream>>>(l1_b1, l1_bn_g, l1_bn_b, l1_bn_m, l1_bn_v, s_l1a, t_l1a, HID, HID_P);
        dim3 s2g((EMB_P + 255) / 256, 1);
        convert_st<<<s2g, 256, 0, stream>>>(l1_b2, l1_bno_g, l1_bno_b, l1_bno_m, l1_bno_v, s_l1b, t_l1b, EMB, EMB_P);
        dim3 s3g((HID_P + 255) / 256, 4);
        convert_st<<<s3g, 256, 0, stream>>>(bs1, bn_g, bn_b, bn_m, bn_v, s1, t1, HID, HID_P);
        dim3 s4g((EMB_P + 255) / 256, 4);
        convert_st<<<s4g, 256, 0, stream>>>(bs2, bno_g, bno_b, bno_m, bno_v, s2, t2, EMB, EMB_P);
    }

    const int gA  = (M_P / 256) * (HID_P / 160); // 784 blocks, N=640 (tile 160)
    const int gB2 = (M_P / 512) * (EMB_P / 160); // 196 blocks, N=320 (tile 160)

    // ---- layer 1 ----
    aggregate_f32in<<<(N * 16 + 255) / 256, 256, 0, stream>>>(x, rowptr, esrc, zin);
    gemm_t160<64><<<gA, 256, 0, stream>>>(zin, wt_l1a, s_l1a, t_l1a, zmid, HID_P, 1);
    gemm_w160<640><<<gB2, 512, 0, stream>>>(zmid, wt_l1b, s_l1b, t_l1b, hbuf, EMB_P, 1);

    // ---- layers 2..5 ----
    for (int i = 0; i < 4; ++i) {
        aggregate_f16<<<(N * (EMB_K / 8) + 255) / 256, 256, 0, stream>>>(hbuf, rowptr, esrc, zin);
        gemm_t160<320><<<gA, 256, 0, stream>>>(
            zin, wt1 + (size_t)i * HID_P * EMB_K, s1 + i * HID_P, t1 + i * HID_P,
            zmid, HID_P, 1);
        gemm_w160<640><<<gB2, 512, 0, stream>>>(
            zmid, wt2 + (size_t)i * EMB_P * HID_P, s2 + i * EMB_P, t2 + i * EMB_P,
            hbuf, EMB_P, (i != 3) ? 1 : 0);
    }

    // ---- pool + classify ----
    pool_classify<<<N_GRAPHS, 64, 0, stream>>>(hbuf, batch, clfW, clfb, out, N);
}

// Round 21
// 588.161 us; speedup vs baseline: 1.0584x; 1.0584x over previous
//
#include <hip/hip_runtime.h>
#include <hip/hip_bf16.h>

// ---------------------------------------------------------------------------
// GIN forward, round 21 — REVERT to r19 (measured best: 588us).
//   r20 lesson (ledger): 2-block residency in practice requires LDS <= ~64KB
//   (78KB tile ran 1-resident; granularity rounds to 80KB, 2x80 = all of LDS
//   doesn't co-schedule). With that + round-quantization (r18) + staged-byte
//   ceiling (r17), r19's configuration is the constrained optimum:
//     - GEMM1: 256x128 tile, 64KB LDS, 2-resident, 980 blocks (47us)
//     - GEMM2: 512x160 tile, 126KB LDS, 196 blocks = 1 round (44us)
//     - fused cursor-write scan, dedup'd B staging, XCD swizzle, EMB_P=320
// ---------------------------------------------------------------------------

#define N_NODES 50000
#define M_P     50176      // 98 * 512 = 196 * 256
#define N_EDGES 200000
#define IN_DIM  64
#define EMB     300
#define HID     600
#define EMB_P   320        // hbuf row stride / GEMM2 N (2 * 160)
#define EMB_K   320        // zin row stride / GEMM1 K (10 * 32)
#define HID_P   640        // GEMM1 N (5 * 128)
#define N_GRAPHS 1024
#define N_CLASS 10
#define BN_EPS  1e-5f

typedef _Float16 half8 __attribute__((ext_vector_type(8)));
typedef float    f32x4 __attribute__((ext_vector_type(4)));

__device__ __forceinline__ void gload16(const void* g, void* l) {
    __builtin_amdgcn_global_load_lds(
        (const __attribute__((address_space(1))) void*)g,
        (__attribute__((address_space(3))) void*)l, 16, 0, 0);
}

// ---------------- CSR build ----------------

__global__ void count_deg_kernel(const int* __restrict__ dst, int* __restrict__ deg, int E) {
    int e = blockIdx.x * blockDim.x + threadIdx.x;
    if (e < E) atomicAdd(&deg[dst[e]], 1);
}

__global__ void block_reduce_kernel(const int* __restrict__ in, int* __restrict__ partials, int n) {
    __shared__ int sm[4];
    const int b = blockIdx.x, t = threadIdx.x;
    const int base = b * 1024;
    int v = 0;
    #pragma unroll
    for (int i = 0; i < 4; ++i) {
        int ix = base + t + i * 256;
        if (ix < n) v += in[ix];
    }
    #pragma unroll
    for (int off = 32; off > 0; off >>= 1) v += __shfl_xor(v, off);
    if ((t & 63) == 0) sm[t >> 6] = v;
    __syncthreads();
    if (t == 0) partials[b] = sm[0] + sm[1] + sm[2] + sm[3];
}

__global__ void scan_partials_kernel(int* __restrict__ partials, int nb) {
    const int t = threadIdx.x;
    int v = (t < nb) ? partials[t] : 0;
    const int orig = v;
    #pragma unroll
    for (int off = 1; off < 64; off <<= 1) {
        int u = __shfl_up(v, off);
        if (t >= off) v += u;
    }
    if (t < nb) partials[t] = v - orig;
}

__global__ void block_scan_kernel(const int* __restrict__ in, const int* __restrict__ partials,
                                  int* __restrict__ out, int* __restrict__ cursor,
                                  int n, int total) {
    __shared__ int sd[1024];
    const int b = blockIdx.x, t = threadIdx.x;
    const int idx = b * 1024 + t;
    const int v = (idx < n) ? in[idx] : 0;
    sd[t] = v;
    __syncthreads();
    #pragma unroll
    for (int off = 1; off < 1024; off <<= 1) {
        int u = (t >= off) ? sd[t - off] : 0;
        __syncthreads();
        sd[t] += u;
        __syncthreads();
    }
    if (idx < n) {
        int ex = partials[b] + sd[t] - v;
        out[idx] = ex;
        cursor[idx] = ex;
    }
    if (b == 0 && t == 0) out[n] = total;
}

__global__ void scatter_edges_kernel(const int* __restrict__ src, const int* __restrict__ dst,
                                     int* __restrict__ cursor, int* __restrict__ esrc, int E) {
    int e = blockIdx.x * blockDim.x + threadIdx.x;
    if (e < E) {
        int d = dst[e];
        int pos = atomicAdd(&cursor[d], 1);
        esrc[pos] = src[e];
    }
}

// ---------------- weight / epilogue-param conversion ----------------

__global__ void convert_w(const float* __restrict__ W, _Float16* __restrict__ Wt,
                          int K, int N, int K_P, int N_P) {
    int b = blockIdx.y;
    int i = blockIdx.x * 256 + threadIdx.x;
    if (i >= N_P * K_P) return;
    int n = i / K_P, k = i % K_P;
    _Float16 v = (_Float16)0.f;
    if (n < N && k < K) v = (_Float16)W[((size_t)b * K + k) * N + n];
    Wt[(size_t)b * N_P * K_P + i] = v;
}

__global__ void convert_st(const float* __restrict__ bias, const float* __restrict__ g,
                           const float* __restrict__ bb, const float* __restrict__ m,
                           const float* __restrict__ v, float* __restrict__ S,
                           float* __restrict__ T, int N, int N_P) {
    int b = blockIdx.y;
    int i = blockIdx.x * 256 + threadIdx.x;
    if (i >= N_P) return;
    float s = 0.f, t = 0.f;
    if (i < N) {
        s = g[b * N + i] * rsqrtf(v[b * N + i] + BN_EPS);
        t = (bias[b * N + i] - m[b * N + i]) * s + bb[b * N + i];
    }
    S[b * N_P + i] = s;
    T[b * N_P + i] = t;
}

// ---------------- aggregation ----------------

__global__ void aggregate_f16(const _Float16* __restrict__ h, const int* __restrict__ rowptr,
                              const int* __restrict__ esrc, _Float16* __restrict__ z) {
    const int NCH = EMB_K / 8;          // 40
    const int NACT = 38;                // ceil(300/8); h cols 300..319 are 0
    int t = blockIdx.x * blockDim.x + threadIdx.x;
    int node = t / NCH;
    int c = t - node * NCH;
    if (node >= N_NODES) return;
    _Float16* zp = z + (size_t)node * EMB_K + c * 8;
    if (c >= NACT) {
        half8 zero = {};
        *(half8*)zp = zero;
        return;
    }
    float a[8];
    half8 v = *(const half8*)(h + (size_t)node * EMB_P + c * 8);
    #pragma unroll
    for (int j = 0; j < 8; ++j) a[j] = (float)v[j];
    int s0 = rowptr[node], s1 = rowptr[node + 1];
    for (int e = s0; e < s1; ++e) {
        half8 u = *(const half8*)(h + (size_t)esrc[e] * EMB_P + c * 8);
        #pragma unroll
        for (int j = 0; j < 8; ++j) a[j] += (float)u[j];
    }
    half8 o;
    #pragma unroll
    for (int j = 0; j < 8; ++j) o[j] = (_Float16)a[j];
    *(half8*)zp = o;
}

__global__ void aggregate_f32in(const float* __restrict__ x, const int* __restrict__ rowptr,
                                const int* __restrict__ esrc, _Float16* __restrict__ z) {
    int t = blockIdx.x * blockDim.x + threadIdx.x;
    int node = t >> 4;
    int c = t & 15;
    if (node >= N_NODES) return;
    float4 a = *(const float4*)(x + (size_t)node * IN_DIM + c * 4);
    int s0 = rowptr[node], s1 = rowptr[node + 1];
    for (int e = s0; e < s1; ++e) {
        float4 u = *(const float4*)(x + (size_t)esrc[e] * IN_DIM + c * 4);
        a.x += u.x; a.y += u.y; a.z += u.z; a.w += u.w;
    }
    _Float16* zp = z + (size_t)node * IN_DIM + c * 4;
    zp[0] = (_Float16)a.x; zp[1] = (_Float16)a.y;
    zp[2] = (_Float16)a.z; zp[3] = (_Float16)a.w;
}

// ---------------- GEMM A (r9 exact): C[M_P][NP], N-tile 128 ----------------
// Block 256x128, 4 waves (wave tile 128x64). LDS 64KB (2-resident). Schedule:
// vmcnt(4|0) -> barrier -> sched_barrier -> stageB(t+1), stageA(t+2) ->
// ds_read + MFMA (setprio).

template<int KP>
__global__ __launch_bounds__(256, 2) void gemm_f16_mfma(
        const _Float16* __restrict__ A, const _Float16* __restrict__ Bt,
        const float* __restrict__ Sc, const float* __restrict__ Tc,
        _Float16* __restrict__ C, int N_P, int do_relu) {
    constexpr int NT = KP / 32;
    __shared__ _Float16 LDS[3 * 8192 + 2 * 4096];   // 64 KB
    _Float16* const ABUF = LDS;
    _Float16* const BBUF = LDS + 3 * 8192;
    const int tid  = threadIdx.x;
    const int wid  = tid >> 6;
    const int lane = tid & 63;

    const int NY  = N_P >> 7;
    const int nwg = gridDim.x;
    const int q = nwg >> 3, r = nwg & 7;
    const int xcd = blockIdx.x & 7, bidx = blockIdx.x >> 3;
    const int wgid = (xcd < r ? xcd * (q + 1) : r * (q + 1) + (xcd - r) * q) + bidx;
    const int mt = wgid / NY;
    const int ntile = wgid - mt * NY;
    const size_t bm0 = (size_t)mt * 256;
    const int    bn0 = ntile * 128;

    const int wr = (wid & 1) * 128;
    const int wc = (wid >> 1) * 64;

    const int fr = lane & 15;
    const int fk = (lane >> 4) * 8;
    const _Float16* gA = A  + (bm0 + fr) * (size_t)KP + fk;
    const _Float16* gB = Bt + ((size_t)bn0 + fr) * (size_t)KP + fk;

    f32x4 acc[8][4];
    #pragma unroll
    for (int m = 0; m < 8; ++m)
        #pragma unroll
        for (int n = 0; n < 4; ++n) acc[m][n] = (f32x4){0.f, 0.f, 0.f, 0.f};

    const int subA = wr >> 4;
    const int subB = wc >> 4;

    auto stageA = [&](int tt) {
        _Float16* lb = ABUF + (tt % 3) * 8192;
        const int k0 = tt * 32;
        #pragma unroll
        for (int j = 0; j < 4; ++j) {
            const int s = wid + 4 * j;
            gload16(gA + (size_t)(s * 16) * KP + k0, lb + s * 512);
        }
    };
    auto stageB = [&](int tt) {
        _Float16* lb = BBUF + (tt & 1) * 4096;
        const int k0 = tt * 32;
        #pragma unroll
        for (int j = 0; j < 2; ++j) {
            const int s = wid + 4 * j;
            gload16(gB + (size_t)(s * 16) * KP + k0, lb + s * 512);
        }
    };

    stageA(0);
    stageB(0);
    if (NT > 1) stageA(1);

    #pragma unroll
    for (int t = 0; t < NT; ++t) {
        if (t + 1 < NT) asm volatile("s_waitcnt vmcnt(4)" ::: "memory");
        else            asm volatile("s_waitcnt vmcnt(0)" ::: "memory");
        __builtin_amdgcn_s_barrier();
        __builtin_amdgcn_sched_barrier(0);
        if (t + 1 < NT) stageB(t + 1);
        if (t + 2 < NT) stageA(t + 2);
        {
            const _Float16* la = ABUF + (t % 3) * 8192;
            const _Float16* lb = BBUF + (t & 1) * 4096;
            half8 af[8], bf[4];
            #pragma unroll
            for (int m = 0; m < 8; ++m)
                af[m] = *(const half8*)(la + (subA + m) * 512 + lane * 8);
            #pragma unroll
            for (int n = 0; n < 4; ++n)
                bf[n] = *(const half8*)(lb + (subB + n) * 512 + lane * 8);
            __builtin_amdgcn_s_setprio(1);
            #pragma unroll
            for (int m = 0; m < 8; ++m)
                #pragma unroll
                for (int n = 0; n < 4; ++n)
                    acc[m][n] = __builtin_amdgcn_mfma_f32_16x16x32_f16(
                        af[m], bf[n], acc[m][n], 0, 0, 0);
            __builtin_amdgcn_s_setprio(0);
        }
    }

    #pragma unroll
    for (int n = 0; n < 4; ++n) {
        const int col = bn0 + wc + n * 16 + (lane & 15);
        const float s = Sc[col], t = Tc[col];
        #pragma unroll
        for (int m = 0; m < 8; ++m) {
            f32x4 v = acc[m][n];
            const size_t rbase = bm0 + wr + m * 16 + (lane >> 4) * 4;
            #pragma unroll
            for (int rr = 0; rr < 4; ++rr) {
                float y = v[rr] * s + t;
                if (do_relu) y = fmaxf(y, 0.f);
                C[(rbase + rr) * (size_t)N_P + col] = (_Float16)y;
            }
        }
    }
}

// ---------------- GEMM B: 512x160 tile (GEMM2, N_P=320) ----------------
// 8 waves, wave tile 128x80. LDS 126KB. No duplicate B loads: waves 0-4
// stage 2 B subtiles each (all 10), waves 5-7 stage A only; per-wave
// vmcnt 6 (w0-4) / 4 (w5-7), wave-uniform branches.

template<int KP>
__global__ __launch_bounds__(512, 1) void gemm_w160(
        const _Float16* __restrict__ A, const _Float16* __restrict__ Bt,
        const float* __restrict__ Sc, const float* __restrict__ Tc,
        _Float16* __restrict__ C, int N_P, int do_relu) {
    constexpr int NT = KP / 32;
    __shared__ _Float16 LDS[3 * 16384 + 3 * 5120];  // 126 KB
    _Float16* const ABUF = LDS;
    _Float16* const BBUF = LDS + 3 * 16384;
    const int tid  = threadIdx.x;
    const int wid  = tid >> 6;                      // 0..7
    const int lane = tid & 63;

    const int NY  = N_P / 160;
    const int nwg = gridDim.x;
    const int q = nwg >> 3, r = nwg & 7;
    const int xcd = blockIdx.x & 7, bidx = blockIdx.x >> 3;
    const int wgid = (xcd < r ? xcd * (q + 1) : r * (q + 1) + (xcd - r) * q) + bidx;
    const int mt = wgid / NY;
    const int ntile = wgid - mt * NY;
    const size_t bm0 = (size_t)mt * 512;
    const int    bn0 = ntile * 160;

    const int wr = (wid & 3) * 128;          // 0/128/256/384
    const int wc = (wid >> 2) * 80;          // 0/80

    const int fr = lane & 15;
    const int fk = (lane >> 4) * 8;
    const _Float16* gA = A  + (bm0 + fr) * (size_t)KP + fk;
    const _Float16* gB = Bt + ((size_t)bn0 + fr) * (size_t)KP + fk;

    f32x4 acc[8][5];
    #pragma unroll
    for (int m = 0; m < 8; ++m)
        #pragma unroll
        for (int n = 0; n < 5; ++n) acc[m][n] = (f32x4){0.f, 0.f, 0.f, 0.f};

    const int subA = wr >> 4;                // 0/8/16/24 (A: 32 subtiles)
    const int subB = wc >> 4;                // 0/5       (B: 10 subtiles)

    auto stage = [&](int tt) {               // w0-4: 6 loads; w5-7: 4 loads
        const int k0 = tt * 32;
        _Float16* la = ABUF + (tt % 3) * 16384;
        #pragma unroll
        for (int j = 0; j < 4; ++j) {        // A subtiles wid + 8j (0..31)
            const int s = wid + 8 * j;
            gload16(gA + (size_t)(s * 16) * KP + k0, la + s * 512);
        }
        if (wid < 5) {                       // B subtiles 2*wid, 2*wid+1 (0..9)
            _Float16* lb = BBUF + (tt % 3) * 5120;
            #pragma unroll
            for (int j = 0; j < 2; ++j) {
                const int s = 2 * wid + j;
                gload16(gB + (size_t)(s * 16) * KP + k0, lb + s * 512);
            }
        }
    };

    stage(0);
    if (NT > 1) stage(1);

    #pragma unroll
    for (int t = 0; t < NT; ++t) {
        if (t + 1 < NT) {
            if (wid < 5) asm volatile("s_waitcnt vmcnt(6)" ::: "memory");
            else         asm volatile("s_waitcnt vmcnt(4)" ::: "memory");
        } else {
            asm volatile("s_waitcnt vmcnt(0)" ::: "memory");
        }
        __builtin_amdgcn_s_barrier();            // all waves' stage(t) landed,
                                                 // all reads of iter t-1 done
        __builtin_amdgcn_sched_barrier(0);       // no hoisting above barrier
        if (t + 2 < NT) stage(t + 2);            // buf (t+2)%3, last read t-1
        {
            const _Float16* la = ABUF + (t % 3) * 16384;
            const _Float16* lb = BBUF + (t % 3) * 5120;
            half8 af[8], bf[5];
            #pragma unroll
            for (int m = 0; m < 8; ++m)
                af[m] = *(const half8*)(la + (subA + m) * 512 + lane * 8);
            #pragma unroll
            for (int n = 0; n < 5; ++n)
                bf[n] = *(const half8*)(lb + (subB + n) * 512 + lane * 8);
            __builtin_amdgcn_s_setprio(1);
            #pragma unroll
            for (int m = 0; m < 8; ++m)
                #pragma unroll
                for (int n = 0; n < 5; ++n)
                    acc[m][n] = __builtin_amdgcn_mfma_f32_16x16x32_f16(
                        af[m], bf[n], acc[m][n], 0, 0, 0);
            __builtin_amdgcn_s_setprio(0);
        }
    }

    #pragma unroll
    for (int n = 0; n < 5; ++n) {
        const int col = bn0 + wc + n * 16 + fr;
        const float s = Sc[col], t = Tc[col];
        #pragma unroll
        for (int m = 0; m < 8; ++m) {
            f32x4 v = acc[m][n];
            const size_t rbase = bm0 + wr + m * 16 + (lane >> 4) * 4;
            #pragma unroll
            for (int rr = 0; rr < 4; ++rr) {
                float y = v[rr] * s + t;
                if (do_relu) y = fmaxf(y, 0.f);
                C[(rbase + rr) * (size_t)N_P + col] = (_Float16)y;
            }
        }
    }
}

// ---------------- mean pool + classifier ----------------

__global__ void pool_classify(const _Float16* __restrict__ h, const int* __restrict__ batch,
                              const float* __restrict__ clfW, const float* __restrict__ clfb,
                              float* __restrict__ out, int n) {
    int g = blockIdx.x;
    __shared__ int s_lo, s_hi;
    __shared__ float pooled[304];
    if (threadIdx.x == 0) {
        int lo = 0, hi = n;
        while (lo < hi) { int mid = (lo + hi) >> 1; if (batch[mid] < g) lo = mid + 1; else hi = mid; }
        s_lo = lo;
        int lo2 = lo, hi2 = n;
        while (lo2 < hi2) { int mid = (lo2 + hi2) >> 1; if (batch[mid] < g + 1) lo2 = mid + 1; else hi2 = mid; }
        s_hi = lo2;
    }
    __syncthreads();
    const int lo = s_lo, hi = s_hi;
    const float inv = 1.0f / fmaxf((float)(hi - lo), 1.0f);
    const int c = threadIdx.x;
    if (c < 38) {
        float a[8] = {0.f, 0.f, 0.f, 0.f, 0.f, 0.f, 0.f, 0.f};
        for (int r = lo; r < hi; ++r) {
            half8 v = *(const half8*)(h + (size_t)r * EMB_P + c * 8);
            #pragma unroll
            for (int j = 0; j < 8; ++j) a[j] += (float)v[j];
        }
        #pragma unroll
        for (int j = 0; j < 8; ++j) pooled[c * 8 + j] = a[j] * inv;
    }
    __syncthreads();
    const int lane = threadIdx.x & 63;
    for (int cc = 0; cc < N_CLASS; ++cc) {
        float p = 0.f;
        for (int d = lane; d < EMB; d += 64) p += pooled[d] * clfW[d * N_CLASS + cc];
        #pragma unroll
        for (int off = 32; off > 0; off >>= 1) p += __shfl_down(p, off);
        if (lane == 0) out[g * N_CLASS + cc] = p + clfb[cc];
    }
}

// ---------------- launch ----------------

extern "C" void kernel_launch(void* const* d_in, const int* in_sizes, int n_in,
                              void* d_out, int out_size, void* d_ws, size_t ws_size,
                              hipStream_t stream) {
    const float* x      = (const float*)d_in[0];
    const int*   ei     = (const int*)d_in[1];
    const int*   batch  = (const int*)d_in[2];
    const float* l1_W1  = (const float*)d_in[3];
    const float* l1_b1  = (const float*)d_in[4];
    const float* l1_bn_g = (const float*)d_in[5];
    const float* l1_bn_b = (const float*)d_in[6];
    const float* l1_bn_m = (const float*)d_in[7];
    const float* l1_bn_v = (const float*)d_in[8];
    const float* l1_W2  = (const float*)d_in[9];
    const float* l1_b2  = (const float*)d_in[10];
    const float* l1_bno_g = (const float*)d_in[11];
    const float* l1_bno_b = (const float*)d_in[12];
    const float* l1_bno_m = (const float*)d_in[13];
    const float* l1_bno_v = (const float*)d_in[14];
    const float* Ws1    = (const float*)d_in[15];
    const float* bs1    = (const float*)d_in[16];
    const float* bn_g   = (const float*)d_in[17];
    const float* bn_b   = (const float*)d_in[18];
    const float* bn_m   = (const float*)d_in[19];
    const float* bn_v   = (const float*)d_in[20];
    const float* Ws2    = (const float*)d_in[21];
    const float* bs2    = (const float*)d_in[22];
    const float* bno_g  = (const float*)d_in[23];
    const float* bno_b  = (const float*)d_in[24];
    const float* bno_m  = (const float*)d_in[25];
    const float* bno_v  = (const float*)d_in[26];
    const float* clfW   = (const float*)d_in[27];
    const float* clfb   = (const float*)d_in[28];
    float* out = (float*)d_out;

    const int N = N_NODES, E = N_EDGES;
    const int* src = ei;
    const int* dst = ei + E;

    char* ws = (char*)d_ws;
    size_t off = 0;
    auto alloc = [&](size_t bytes) -> void* {
        void* p = ws + off;
        off += (bytes + 255) & ~(size_t)255;
        return p;
    };
    _Float16* zmid  = (_Float16*)alloc((size_t)M_P * HID_P * 2);   // 64 MB
    _Float16* hbuf  = (_Float16*)alloc((size_t)M_P * EMB_P * 2);   // 32 MB
    _Float16* zin   = (_Float16*)alloc((size_t)M_P * EMB_K * 2);   // 32 MB
    _Float16* wt_l1a = (_Float16*)alloc((size_t)HID_P * IN_DIM * 2);
    _Float16* wt_l1b = (_Float16*)alloc((size_t)EMB_P * HID_P * 2);
    _Float16* wt1   = (_Float16*)alloc((size_t)4 * HID_P * EMB_K * 2);
    _Float16* wt2   = (_Float16*)alloc((size_t)4 * EMB_P * HID_P * 2);
    float* s_l1a = (float*)alloc(HID_P * 4); float* t_l1a = (float*)alloc(HID_P * 4);
    float* s_l1b = (float*)alloc(EMB_P * 4); float* t_l1b = (float*)alloc(EMB_P * 4);
    float* s1 = (float*)alloc(4 * HID_P * 4); float* t1 = (float*)alloc(4 * HID_P * 4);
    float* s2 = (float*)alloc(4 * EMB_P * 4); float* t2 = (float*)alloc(4 * EMB_P * 4);
    int* deg      = (int*)alloc((size_t)N * 4);
    int* rowptr   = (int*)alloc((size_t)(N + 1) * 4);
    int* cursor   = (int*)alloc((size_t)N * 4);
    int* esrc     = (int*)alloc((size_t)E * 4);
    int* partials = (int*)alloc(64 * 4);
    (void)ws_size; (void)n_in; (void)in_sizes; (void)out_size;

    const int NB_SCAN = (N + 1023) / 1024;   // 49

    // ---- CSR ----
    hipMemsetAsync(deg, 0, (size_t)N * 4, stream);
    count_deg_kernel<<<(E + 255) / 256, 256, 0, stream>>>(dst, deg, E);
    block_reduce_kernel<<<NB_SCAN, 256, 0, stream>>>(deg, partials, N);
    scan_partials_kernel<<<1, 64, 0, stream>>>(partials, NB_SCAN);
    block_scan_kernel<<<NB_SCAN, 1024, 0, stream>>>(deg, partials, rowptr, cursor, N, E);
    scatter_edges_kernel<<<(E + 255) / 256, 256, 0, stream>>>(src, dst, cursor, esrc, E);

    // ---- weight & epilogue-param conversion ----
    {
        dim3 g1((HID_P * IN_DIM + 255) / 256, 1);
        convert_w<<<g1, 256, 0, stream>>>(l1_W1, wt_l1a, IN_DIM, HID, IN_DIM, HID_P);
        dim3 g2((EMB_P * HID_P + 255) / 256, 1);
        convert_w<<<g2, 256, 0, stream>>>(l1_W2, wt_l1b, HID, EMB, HID_P, EMB_P);
        dim3 g3((HID_P * EMB_K + 255) / 256, 4);
        convert_w<<<g3, 256, 0, stream>>>(Ws1, wt1, EMB, HID, EMB_K, HID_P);
        dim3 g4((EMB_P * HID_P + 255) / 256, 4);
        convert_w<<<g4, 256, 0, stream>>>(Ws2, wt2, HID, EMB, HID_P, EMB_P);

        dim3 s1g((HID_P + 255) / 256, 1);
        convert_st<<<s1g, 256, 0, stream>>>(l1_b1, l1_bn_g, l1_bn_b, l1_bn_m, l1_bn_v, s_l1a, t_l1a, HID, HID_P);
        dim3 s2g((EMB_P + 255) / 256, 1);
        convert_st<<<s2g, 256, 0, stream>>>(l1_b2, l1_bno_g, l1_bno_b, l1_bno_m, l1_bno_v, s_l1b, t_l1b, EMB, EMB_P);
        dim3 s3g((HID_P + 255) / 256, 4);
        convert_st<<<s3g, 256, 0, stream>>>(bs1, bn_g, bn_b, bn_m, bn_v, s1, t1, HID, HID_P);
        dim3 s4g((EMB_P + 255) / 256, 4);
        convert_st<<<s4g, 256, 0, stream>>>(bs2, bno_g, bno_b, bno_m, bno_v, s2, t2, EMB, EMB_P);
    }

    const int gm  = M_P / 256;                   // 196
    const int gA  = gm * (HID_P / 128);          // 980 blocks, N=640 (tile 128)
    const int gB2 = (M_P / 512) * (EMB_P / 160); // 196 blocks, N=320 (tile 160)

    // ---- layer 1 ----
    aggregate_f32in<<<(N * 16 + 255) / 256, 256, 0, stream>>>(x, rowptr, esrc, zin);
    gemm_f16_mfma<64><<<gA, 256, 0, stream>>>(zin, wt_l1a, s_l1a, t_l1a, zmid, HID_P, 1);
    gemm_w160<640><<<gB2, 512, 0, stream>>>(zmid, wt_l1b, s_l1b, t_l1b, hbuf, EMB_P, 1);

    // ---- layers 2..5 ----
    for (int i = 0; i < 4; ++i) {
        aggregate_f16<<<(N * (EMB_K / 8) + 255) / 256, 256, 0, stream>>>(hbuf, rowptr, esrc, zin);
        gemm_f16_mfma<320><<<gA, 256, 0, stream>>>(
            zin, wt1 + (size_t)i * HID_P * EMB_K, s1 + i * HID_P, t1 + i * HID_P,
            zmid, HID_P, 1);
        gemm_w160<640><<<gB2, 512, 0, stream>>>(
            zmid, wt2 + (size_t)i * EMB_P * HID_P, s2 + i * EMB_P, t2 + i * EMB_P,
            hbuf, EMB_P, (i != 3) ? 1 : 0);
    }

    // ---- pool + classify ----
    pool_classify<<<N_GRAPHS, 64, 0, stream>>>(hbuf, batch, clfW, clfb, out, N);
}